// Round 11
// baseline (7159.666 us; speedup 1.0000x reference)
//
#include <hip/hip_runtime.h>
#include <cstdint>

// ---------------------------------------------------------------------------
// SA_Layer_PN2: centers + 32-NN + (gather,concat) -> 3x [1x1conv -> BN -> ReLU]
// -> max over k.  f32 math, bf16 activation storage.
// R10 results: knn (256,1) despill PASSED (bits preserved) — frozen with it.
// k_l3 531us @ VALUBusy 16%: z-loads inside the c4 loop (32 dependent 8B
// loads, lane-stride 128B). R11: hoist row to pk[8] registers (k_l2's proven
// pattern, 8-deep MLP). Everything else byte-identical.
// ---------------------------------------------------------------------------

constexpr int B_ = 8;
constexpr int N_ = 8192;
constexpr int M_ = 2048;
constexpr int K_ = 32;
constexpr float NTINV = 1.0f / 524288.0f;   // 1 / (B*M*K)
constexpr float BN_EPS = 1e-5f;

// workspace layout (bytes)
constexpr size_t OFF_KNN   = 0;             // int32 [B*M*K]          2,097,152
constexpr size_t OFF_FEATB = 2097152;       // bf16 [B*N*64]          8,388,608
constexpr size_t OFF_MAXZ  = 2097152;       // f32 [16384*128] ALIASES featB (dead after k_l1)
constexpr size_t OFF_XYZ4  = 10485760;      // f32x4 [B*N]            2,097,152
constexpr size_t OFF_XN    = 12582912;      // f32 [B*N]                262,144
constexpr size_t OFF_WT1   = 12845056;      // f32 [67*64]
constexpr size_t OFF_WT2   = 12862208;      // f32 [64*64]
constexpr size_t OFF_WT3   = 12878592;      // f32 [64*128]
constexpr size_t OFF_GST   = 12911360;      // f32 [512]
constexpr size_t OFF_SS1   = 12913408;      // f32 [128]
constexpr size_t OFF_SS2   = 12913920;      // f32 [128]
constexpr size_t OFF_Z     = 12914432;      // bf16 [524288*64]      67,108,864
constexpr size_t WS_NEED   = 80023296;      // ~80 MB total

// ---- bf16 helpers (RNE) ----------------------------------------------------
__device__ __forceinline__ unsigned int pack_bf2(float a, float b) {
  unsigned int ua = __float_as_uint(a);
  unsigned int ub = __float_as_uint(b);
  ua = ua + 0x7FFFu + ((ua >> 16) & 1u);
  ub = ub + 0x7FFFu + ((ub >> 16) & 1u);
  return (ua >> 16) | (ub & 0xFFFF0000u);
}
__device__ __forceinline__ float bf_lo(unsigned int u) { return __uint_as_float(u << 16); }
__device__ __forceinline__ float bf_hi(unsigned int u) { return __uint_as_float(u & 0xFFFF0000u); }

// ---------------------------------------------------------------------------
// k_prep: featB (bf16) pack, xyz4 pad, xyz norms, weight transposes, centers
// ---------------------------------------------------------------------------
__global__ __launch_bounds__(256) void k_prep(
    const float* __restrict__ xyz, const float* __restrict__ feat,
    const float* __restrict__ W1, const float* __restrict__ W2,
    const float* __restrict__ W3,
    unsigned short* __restrict__ featB, float* __restrict__ xyz4,
    float* __restrict__ xn,
    float* __restrict__ wt1, float* __restrict__ wt2, float* __restrict__ wt3,
    float* __restrict__ cent_out)
{
  const int id = blockIdx.x * 256 + threadIdx.x;
  if (id < B_ * N_) {
    const int b = id >> 13;
    const int n = id & (N_ - 1);
    const float* pp = xyz + id * 3;
    const float x = pp[0], y = pp[1], z = pp[2];
    xn[id] = x * x + y * y + z * z;
    float4* x4 = (float4*)xyz4;
    x4[id] = make_float4(x, y, z, 0.0f);
    const float* fsrc = feat + b * 64 * N_ + n;
    unsigned short* fdst = featB + (size_t)id * 64;
#pragma unroll
    for (int c8 = 0; c8 < 8; ++c8) {
      uint4 v;
      v.x = pack_bf2(fsrc[(c8 * 8 + 0) * N_], fsrc[(c8 * 8 + 1) * N_]);
      v.y = pack_bf2(fsrc[(c8 * 8 + 2) * N_], fsrc[(c8 * 8 + 3) * N_]);
      v.z = pack_bf2(fsrc[(c8 * 8 + 4) * N_], fsrc[(c8 * 8 + 5) * N_]);
      v.w = pack_bf2(fsrc[(c8 * 8 + 6) * N_], fsrc[(c8 * 8 + 7) * N_]);
      *(uint4*)(fdst + c8 * 8) = v;
    }
  } else if (id < B_ * N_ + B_ * M_) {
    const int idx = id - B_ * N_;
    const int b = idx >> 11;
    const int m = idx & (M_ - 1);
    const int ic = (int)(((long long)m * (N_ - 1)) / (M_ - 1));
    const float* cp = xyz + (b * N_ + ic) * 3;
    float* dst = cent_out + idx * 3;
    dst[0] = cp[0]; dst[1] = cp[1]; dst[2] = cp[2];
  } else if (id < 81920 + 4288) {
    const int i = id - 81920;
    const int c = i >> 6, o = i & 63;
    wt1[i] = W1[o * 67 + c];
  } else if (id < 86208 + 4096) {
    const int i = id - 86208;
    const int c = i >> 6, o = i & 63;
    wt2[c * 64 + o] = W2[o * 64 + c];
  } else if (id < 90304 + 8192) {
    const int i = id - 90304;
    const int c = i >> 7, o = i & 127;
    wt3[c * 128 + o] = W3[o * 64 + c];
  }
}

// ---------------------------------------------------------------------------
// k_knn: R2-passing source + (256,1) despill — FROZEN (R10 verified bits
// preserved, no scratch). Do not touch.
// ---------------------------------------------------------------------------
__global__ __launch_bounds__(256, 1) void k_knn(
    const float* __restrict__ xyz, const float* __restrict__ xn,
    int* __restrict__ knn)
{
  constexpr int CAP = 2048;
  __shared__ unsigned int hist[512];
  __shared__ unsigned long long keys[CAP];
  __shared__ int sh_cnt, sh_B, wsum[4];

  const int t = threadIdx.x;
  const int bid = blockIdx.x;
  const int b = bid >> 9;
  const int m0 = (bid & 511) * 4;

  float cx[4], cy[4], cz[4], cb[4];
#pragma unroll
  for (int s = 0; s < 4; ++s) {
    const int m = m0 + s;
    const int ic = (int)(((long long)m * (N_ - 1)) / (M_ - 1));
    const float* cp = xyz + (b * N_ + ic) * 3;
    cx[s] = cp[0]; cy[s] = cp[1]; cz[s] = cp[2];
    cb[s] = cx[s] * cx[s] + cy[s] * cy[s] + cz[s] * cz[s];
  }

  unsigned int u[4][32];
  unsigned int umin[4] = {0xFFFFFFFFu, 0xFFFFFFFFu, 0xFFFFFFFFu, 0xFFFFFFFFu};
#pragma unroll
  for (int j = 0; j < 32; ++j) {
    const int n = t + 256 * j;
    const float* pp = xyz + (b * N_ + n) * 3;
    const float x = pp[0], y = pp[1], z = pp[2];
    const float xv = xn[b * N_ + n];
#pragma unroll
    for (int s = 0; s < 4; ++s) {
      const float dot = cx[s] * x + cy[s] * y + cz[s] * z;
      const float d2 = (cb[s] + xv) - 2.0f * dot;      // same formula as ref
      const unsigned int bits = __float_as_uint(d2);
      const unsigned int key = bits ^ ((unsigned int)((int)bits >> 31) | 0x80000000u);
      u[s][j] = key;
      umin[s] = umin[s] < key ? umin[s] : key;
    }
  }

  const int row_base = (b * M_ + m0) * K_;
#pragma unroll 1
  for (int s = 0; s < 4; ++s) {
    int* row = knn + row_base + s * K_;
    __syncthreads();
    hist[t] = 0; hist[t + 256] = 0;
    if (t == 0) sh_cnt = 0;
    __syncthreads();
    atomicAdd(&hist[umin[s] >> 23], 1u);
    __syncthreads();
    if (t < 64) {
      unsigned int h8[8]; unsigned int sum = 0;
#pragma unroll
      for (int q = 0; q < 8; ++q) { h8[q] = hist[t * 8 + q]; sum += h8[q]; }
      unsigned int incl = sum;
#pragma unroll
      for (int off = 1; off < 64; off <<= 1) {
        unsigned int w = __shfl_up(incl, off);
        if (t >= off) incl += w;
      }
      unsigned int run = incl - sum;
      int Bq = -1;
#pragma unroll
      for (int q = 0; q < 8; ++q) { run += h8[q]; if (Bq < 0 && run >= 33) Bq = t * 8 + q; }
      unsigned long long bal = __ballot(Bq >= 0);
      int src = __ffsll((long long)bal) - 1;
      int Bsel = __shfl(Bq, src);
      if (t == 0) sh_B = Bsel;
    }
    __syncthreads();
    const unsigned int Bbin = (unsigned int)sh_B;

    int cc = 0;
#pragma unroll
    for (int j = 0; j < 32; ++j) cc += ((u[s][j] >> 23) <= Bbin) ? 1 : 0;
#pragma unroll
    for (int off = 1; off < 64; off <<= 1) cc += __shfl_xor(cc, off);
    if ((t & 63) == 0) wsum[t >> 6] = cc;
    __syncthreads();
    const int total = wsum[0] + wsum[1] + wsum[2] + wsum[3];

    if (total <= CAP) {
#pragma unroll
      for (int j = 0; j < 32; ++j) {
        if ((u[s][j] >> 23) <= Bbin) {
          const int pos = atomicAdd(&sh_cnt, 1);
          keys[pos] = ((unsigned long long)u[s][j] << 32) | (unsigned int)(t + 256 * j);
        }
      }
      __syncthreads();
      const int C = sh_cnt;
      for (int i = t; i < C; i += 256) {
        const unsigned long long k = keys[i];
        int r = 0;
        for (int q = 0; q < C; ++q) r += (keys[q] < k) ? 1 : 0;
        if (r < K_) row[r] = (int)(k & 0xFFFFFFFFull);
      }
      __syncthreads();
    } else {
      // slow exact fallback (practically never taken)
      unsigned int uu[32];
#pragma unroll
      for (int j = 0; j < 32; ++j) uu[j] = u[s][j];
#pragma unroll 1
      for (int r = 0; r < K_; ++r) {
        unsigned long long best = 0xFFFFFFFFFFFFFFFFull;
#pragma unroll
        for (int j = 0; j < 32; ++j) {
          unsigned long long k = ((unsigned long long)uu[j] << 32) | (unsigned int)(t + 256 * j);
          best = (k < best) ? k : best;
        }
#pragma unroll
        for (int off = 1; off < 64; off <<= 1) {
          unsigned long long o = __shfl_xor(best, off);
          best = (o < best) ? o : best;
        }
        if ((t & 63) == 0) keys[t >> 6] = best;
        __syncthreads();
        unsigned long long b01 = keys[0] < keys[1] ? keys[0] : keys[1];
        unsigned long long b23 = keys[2] < keys[3] ? keys[2] : keys[3];
        best = b01 < b23 ? b01 : b23;
        if (t == 0) row[r] = (int)(best & 0xFFFFFFFFull);
        const int n_match = (int)(best & 0xFFFFFFFFull);
#pragma unroll
        for (int j = 0; j < 32; ++j)
          if ((t + 256 * j) == n_match) uu[j] = 0xFFFFFFFFu;
        __syncthreads();
      }
    }
  }
}

// ---------------------------------------------------------------------------
// k_l1 v4: cooperative LDS staging of gathered bf16 rows (coalesced 128B
// segments, 8 lanes/row), then 1 pt/lane GEMM 67->64 in two 32-ch chunks.
// ---------------------------------------------------------------------------
__global__ __launch_bounds__(256) void k_l1(
    const float* __restrict__ xyz4, const unsigned short* __restrict__ featB,
    const int* __restrict__ knn, const float* __restrict__ centers,
    const float* __restrict__ Wt, const float* __restrict__ bias,
    unsigned short* __restrict__ zout)
{
  __shared__ unsigned short rows[256 * 72];   // 144B row stride, 36.9 KB
  const int t = threadIdx.x;
  const int p0 = blockIdx.x * 256;            // 2048 blocks

  // stage: 8 rounds x 32 rows; thread t -> row 32k+(t>>3), 16B chunk (t&7)
  const int rb = t >> 3, ci = t & 7;
#pragma unroll
  for (int k = 0; k < 8; ++k) {
    const int ri = k * 32 + rb;
    const int pr = p0 + ri;
    const int bb = pr >> 16;
    const int nnr = knn[pr];
    const uint4* src = (const uint4*)(featB + ((size_t)bb * N_ + nnr) * 64);
    *(uint4*)&rows[ri * 72 + ci * 8] = src[ci];
  }

  const int p = p0 + t;
  const int b = p >> 16;
  const int m = (p & 65535) >> 5;
  const int nn = knn[p];
  const float4 pv = ((const float4*)xyz4)[b * N_ + nn];
  const float* cp = centers + (b * M_ + m) * 3;
  const float l0 = pv.x - cp[0];
  const float l1v = pv.y - cp[1];
  const float l2v = pv.z - cp[2];
  __syncthreads();

  const unsigned short* myrow = rows + t * 72;
  unsigned short* zp = zout + (size_t)p * 64;

#pragma unroll 1
  for (int chunk = 0; chunk < 2; ++chunk) {
    const int ob = chunk * 32;
    float acc[32];
    const float* w0 = Wt + ob;
    const float* w1 = Wt + 64 + ob;
    const float* w2 = Wt + 128 + ob;
#pragma unroll
    for (int i = 0; i < 32; ++i)
      acc[i] = fmaf(l0, w0[i], fmaf(l1v, w1[i], fmaf(l2v, w2[i], bias[ob + i])));

#pragma unroll 1
    for (int r = 0; r < 8; ++r) {
      const uint4 v = *(const uint4*)(myrow + r * 8);
      const unsigned int uu[4] = {v.x, v.y, v.z, v.w};
#pragma unroll
      for (int h2 = 0; h2 < 4; ++h2) {
        const int c = 3 + r * 8 + h2 * 2;
        const float f0 = bf_lo(uu[h2]);
        const float f1 = bf_hi(uu[h2]);
        const float* wa = Wt + c * 64 + ob;
        const float* wb = wa + 64;
#pragma unroll
        for (int i = 0; i < 32; ++i)
          acc[i] = fmaf(f0, wa[i], fmaf(f1, wb[i], acc[i]));
      }
    }

    uint4* zo = (uint4*)(zp + ob);
#pragma unroll
    for (int r = 0; r < 4; ++r) {
      uint4 o4;
      o4.x = pack_bf2(acc[r * 8 + 0], acc[r * 8 + 1]);
      o4.y = pack_bf2(acc[r * 8 + 2], acc[r * 8 + 3]);
      o4.z = pack_bf2(acc[r * 8 + 4], acc[r * 8 + 5]);
      o4.w = pack_bf2(acc[r * 8 + 6], acc[r * 8 + 7]);
      zo[r] = o4;
    }
  }
}

// ---------------------------------------------------------------------------
// k_l2: IN-PLACE GEMM 64->64, one point per lane, output in two 32-ch chunks.
// ---------------------------------------------------------------------------
__global__ __launch_bounds__(256) void k_l2(
    unsigned short* __restrict__ z, const float* __restrict__ Wt,
    const float* __restrict__ bias, const float* __restrict__ ss)
{
  const int p = blockIdx.x * 256 + threadIdx.x;
  unsigned short* zp = z + (size_t)p * 64;
  const uint4* zv = (const uint4*)zp;

  uint4 pk[8];
#pragma unroll
  for (int r = 0; r < 8; ++r) pk[r] = zv[r];

#pragma unroll 1
  for (int chunk = 0; chunk < 2; ++chunk) {
    const int ob = chunk * 32;
    float acc[32];
#pragma unroll
    for (int i = 0; i < 32; ++i) acc[i] = bias[ob + i];

#pragma unroll 1
    for (int r = 0; r < 8; ++r) {
      const unsigned int uu[4] = {pk[r].x, pk[r].y, pk[r].z, pk[r].w};
#pragma unroll
      for (int h2 = 0; h2 < 4; ++h2) {
        const int c0 = r * 8 + h2 * 2;
        const float f0 = fmaxf(0.0f, fmaf(bf_lo(uu[h2]), ss[c0], ss[64 + c0]));
        const float f1 = fmaxf(0.0f, fmaf(bf_hi(uu[h2]), ss[c0 + 1], ss[64 + c0 + 1]));
        const float* w0 = Wt + c0 * 64 + ob;
        const float* w1 = w0 + 64;
#pragma unroll
        for (int i = 0; i < 32; ++i)
          acc[i] = fmaf(f0, w0[i], fmaf(f1, w1[i], acc[i]));
      }
    }

    uint4* zo = (uint4*)(zp + ob);
#pragma unroll
    for (int r = 0; r < 4; ++r) {
      uint4 o4;
      o4.x = pack_bf2(acc[r * 8 + 0], acc[r * 8 + 1]);
      o4.y = pack_bf2(acc[r * 8 + 2], acc[r * 8 + 3]);
      o4.z = pack_bf2(acc[r * 8 + 4], acc[r * 8 + 5]);
      o4.w = pack_bf2(acc[r * 8 + 6], acc[r * 8 + 7]);
      zo[r] = o4;
    }
  }
}

// ---------------------------------------------------------------------------
// k_stats2: scan z (bf16), per-channel sum/sumsq -> gstats[0..127].
// ---------------------------------------------------------------------------
__global__ __launch_bounds__(256) void k_stats2(
    const unsigned short* __restrict__ z, float* __restrict__ gstats)
{
  __shared__ float ls[128];
  const int t = threadIdx.x;
  const int lane = t & 63;
  const int cq = t & 3;
  if (t < 128) ls[t] = 0.0f;
  __syncthreads();

  float s[16], q[16];
#pragma unroll
  for (int i = 0; i < 16; ++i) { s[i] = 0.0f; q[i] = 0.0f; }

  const int row0 = blockIdx.x * 1024 + (t >> 2);   // 512 blocks
#pragma unroll 1
  for (int it = 0; it < 16; ++it) {
    const int p = row0 + it * 64;
    const uint4* zp = (const uint4*)(z + (size_t)p * 64 + cq * 16);
    const uint4 v0 = zp[0];
    const uint4 v1 = zp[1];
    const unsigned int uu[8] = {v0.x, v0.y, v0.z, v0.w, v1.x, v1.y, v1.z, v1.w};
#pragma unroll
    for (int h2 = 0; h2 < 8; ++h2) {
      const float f0 = bf_lo(uu[h2]);
      const float f1 = bf_hi(uu[h2]);
      s[h2 * 2] += f0;     q[h2 * 2] = fmaf(f0, f0, q[h2 * 2]);
      s[h2 * 2 + 1] += f1; q[h2 * 2 + 1] = fmaf(f1, f1, q[h2 * 2 + 1]);
    }
  }

#pragma unroll
  for (int i = 0; i < 16; ++i) {
    float sv = s[i], qv = q[i];
#pragma unroll
    for (int off = 4; off < 64; off <<= 1) {
      sv += __shfl_xor(sv, off);
      qv += __shfl_xor(qv, off);
    }
    if (lane < 4) {
      atomicAdd(&ls[cq * 16 + i], sv);
      atomicAdd(&ls[64 + cq * 16 + i], qv);
    }
  }
  __syncthreads();
  if (t < 128) atomicAdd(&gstats[t], ls[t]);
}

// ---------------------------------------------------------------------------
// k_l3 v4: GEMM 64->128 with the z row HOISTED into pk[8] registers (8-deep
// MLP, k_l2's proven load pattern), then fully-unrolled c4 loop reads from
// registers. Epilogue unchanged from v3 (LDS transpose, sequential reduce).
// ---------------------------------------------------------------------------
__global__ __launch_bounds__(256) void k_l3(
    const unsigned short* __restrict__ zin, const float* __restrict__ Wt,
    const float* __restrict__ bias, const float* __restrict__ ss,
    const float* __restrict__ gvec, float* __restrict__ maxz,
    float* __restrict__ gstats)
{
  constexpr int PITCH = 129;                 // odd pitch: 2-way (free) banks
  __shared__ float tile[64 * PITCH];         // 33.0 KB
  __shared__ float ls[256];
  const int t = threadIdx.x;
  const int lane = t & 63;
  const int wv = t >> 6;
  const int ob = wv * 32;
  const int p0 = blockIdx.x * 128;           // 4096 blocks, 128 points each

  const int ch = t & 127;                    // epilogue mapping
  const int bmg = t >> 7;                    // 0..1 (which 32-pt group)
  const bool um = (gvec[ch] >= 0.0f);
  float s_acc = 0.0f, q_acc = 0.0f;
  ls[t] = 0.0f;

#pragma unroll 1
  for (int g = 0; g < 2; ++g) {
    const int pbase = p0 + g * 64 + lane;
    const uint4* zv = (const uint4*)(zin + (size_t)pbase * 64);

    uint4 pk[8];
#pragma unroll
    for (int r = 0; r < 8; ++r) pk[r] = zv[r];

    float acc[32];
#pragma unroll
    for (int i = 0; i < 32; ++i) acc[i] = 0.0f;

#pragma unroll
    for (int c4 = 0; c4 < 16; ++c4) {
      const unsigned int wlo = (c4 & 1) ? pk[c4 >> 1].z : pk[c4 >> 1].x;
      const unsigned int whi = (c4 & 1) ? pk[c4 >> 1].w : pk[c4 >> 1].y;
      float ha[4];
      ha[0] = bf_lo(wlo); ha[1] = bf_hi(wlo);
      ha[2] = bf_lo(whi); ha[3] = bf_hi(whi);
#pragma unroll
      for (int ci = 0; ci < 4; ++ci) {
        const int c = c4 * 4 + ci;
        const float f0 = fmaxf(0.0f, fmaf(ha[ci], ss[c], ss[64 + c]));
        const float* wr = Wt + c * 128 + ob;
#pragma unroll
        for (int i = 0; i < 32; ++i)
          acc[i] = fmaf(f0, wr[i], acc[i]);
      }
    }

    __syncthreads();   // previous read phase done (and ls init on g=0)
    float* tp = tile + lane * PITCH + ob;
#pragma unroll
    for (int i = 0; i < 32; ++i) tp[i] = acc[i] + bias[ob + i];
    __syncthreads();

    // read phase: thread -> (bmg, ch); 32 sequential points, no shuffles
    const float* rp = tile + (bmg * 32) * PITCH + ch;
    float x = rp[0];
    float sl = 0.0f, ql = 0.0f;
#pragma unroll
    for (int j = 0; j < 32; ++j) {
      const float v = rp[j * PITCH];
      sl += v;
      ql = fmaf(v, v, ql);
      x = um ? fmaxf(x, v) : fminf(x, v);
    }
    s_acc += sl;
    q_acc += ql;
    const int bm = blockIdx.x * 4 + g * 2 + bmg;
    maxz[(size_t)bm * 128 + ch] = x;
  }

  atomicAdd(&ls[ch], s_acc);
  atomicAdd(&ls[128 + ch], q_acc);
  __syncthreads();
  atomicAdd(&gstats[t], ls[t]);              // 256 slots: s[0..127], q[128..255]
}

// ---------------------------------------------------------------------------
// k_bnfin: scale = g*rsqrt(var+eps), shift = be - mu*scale  (64 channels)
// ---------------------------------------------------------------------------
__global__ void k_bnfin(const float* __restrict__ gstats,
                        const float* __restrict__ g, const float* __restrict__ be,
                        float* __restrict__ ss)
{
  const int t = threadIdx.x;  // 64
  const float s = gstats[t], q = gstats[64 + t];
  const float mu = s * NTINV;
  const float var = q * NTINV - mu * mu;
  const float scale = g[t] * rsqrtf(var + BN_EPS);
  ss[t] = scale;
  ss[64 + t] = be[t] - mu * scale;
}

// ---------------------------------------------------------------------------
// k_final: finalize BN3, apply to pooled extremes, ReLU, transpose to (B,128,M)
// gstats layout here: s at [ch], q at [128+ch].
// ---------------------------------------------------------------------------
__global__ __launch_bounds__(256) void k_final(
    const float* __restrict__ maxz, const float* __restrict__ gstats,
    const float* __restrict__ g, const float* __restrict__ be,
    float* __restrict__ out)
{
  __shared__ float sc[128], sh[128];
  __shared__ float tile[128][65];
  const int t = threadIdx.x;
  const int b = blockIdx.x >> 5;
  const int m0 = (blockIdx.x & 31) * 64;
  if (t < 128) {
    const float s = gstats[t], q = gstats[128 + t];
    const float mu = s * NTINV;
    const float var = q * NTINV - mu * mu;
    const float scale = g[t] * rsqrtf(var + BN_EPS);
    sc[t] = scale;
    sh[t] = be[t] - mu * scale;
  }
  __syncthreads();
  const float* src = maxz + (size_t)(b * M_ + m0) * 128;
#pragma unroll
  for (int r = 0; r < 8; ++r) {
    const int flat = r * 1024 + t * 4;
    const int ml = flat >> 7;
    const int o = flat & 127;
    const float4 v = *(const float4*)(src + flat);
    tile[o + 0][ml] = fmaxf(0.0f, fmaf(v.x, sc[o + 0], sh[o + 0]));
    tile[o + 1][ml] = fmaxf(0.0f, fmaf(v.y, sc[o + 1], sh[o + 1]));
    tile[o + 2][ml] = fmaxf(0.0f, fmaf(v.z, sc[o + 2], sh[o + 2]));
    tile[o + 3][ml] = fmaxf(0.0f, fmaf(v.w, sc[o + 3], sh[o + 3]));
  }
  __syncthreads();
  const int o = t >> 1;
  const int mh = (t & 1) * 32;
  float* dst = out + B_ * M_ * 3 + (size_t)(b * 128 + o) * M_ + m0 + mh;
#pragma unroll
  for (int q = 0; q < 8; ++q) {
    float4 v;
    v.x = tile[o][mh + q * 4 + 0];
    v.y = tile[o][mh + q * 4 + 1];
    v.z = tile[o][mh + q * 4 + 2];
    v.w = tile[o][mh + q * 4 + 3];
    *(float4*)(dst + q * 4) = v;
  }
}

// ---------------------------------------------------------------------------
extern "C" void kernel_launch(void* const* d_in, const int* in_sizes, int n_in,
                              void* d_out, int out_size, void* d_ws, size_t ws_size,
                              hipStream_t stream) {
  (void)in_sizes; (void)n_in; (void)out_size;
  if (ws_size < WS_NEED) return;  // safety: fail cleanly, not with a memfault

  const float* xyz = (const float*)d_in[0];
  const float* feat = (const float*)d_in[1];
  const float* W1 = (const float*)d_in[2];
  const float* b1 = (const float*)d_in[3];
  const float* g1 = (const float*)d_in[4];
  const float* be1 = (const float*)d_in[5];
  const float* W2 = (const float*)d_in[6];
  const float* b2 = (const float*)d_in[7];
  const float* g2 = (const float*)d_in[8];
  const float* be2 = (const float*)d_in[9];
  const float* W3 = (const float*)d_in[10];
  const float* b3 = (const float*)d_in[11];
  const float* g3 = (const float*)d_in[12];
  const float* be3 = (const float*)d_in[13];
  float* out = (float*)d_out;
  char* ws = (char*)d_ws;

  int* knn = (int*)(ws + OFF_KNN);
  unsigned short* featB = (unsigned short*)(ws + OFF_FEATB);
  float* maxz = (float*)(ws + OFF_MAXZ);     // aliases featB (dead after k_l1)
  float* xyz4 = (float*)(ws + OFF_XYZ4);
  float* xn = (float*)(ws + OFF_XN);
  float* wt1 = (float*)(ws + OFF_WT1);
  float* wt2 = (float*)(ws + OFF_WT2);
  float* wt3 = (float*)(ws + OFF_WT3);
  float* gst = (float*)(ws + OFF_GST);
  float* ss1 = (float*)(ws + OFF_SS1);
  float* ss2 = (float*)(ws + OFF_SS2);
  unsigned short* z = (unsigned short*)(ws + OFF_Z);

  hipMemsetAsync(gst, 0, 512 * sizeof(float), stream);
  k_prep<<<385, 256, 0, stream>>>(xyz, feat, W1, W2, W3, featB, xyz4, xn,
                                  wt1, wt2, wt3, out);
  k_knn<<<4096, 256, 0, stream>>>(xyz, xn, knn);
  k_l1<<<2048, 256, 0, stream>>>(xyz4, featB, knn, out, wt1, b1, z);
  k_stats2<<<512, 256, 0, stream>>>(z, gst);           // layer-1 stats
  k_bnfin<<<1, 64, 0, stream>>>(gst, g1, be1, ss1);
  k_l2<<<2048, 256, 0, stream>>>(z, wt2, b2, ss1);
  k_stats2<<<512, 256, 0, stream>>>(z, gst + 128);     // layer-2 stats
  k_bnfin<<<1, 64, 0, stream>>>(gst + 128, g2, be2, ss2);
  k_l3<<<4096, 256, 0, stream>>>(z, wt3, b3, ss2, g3, maxz, gst + 256);
  k_final<<<256, 256, 0, stream>>>(maxz, gst + 256, g3, be3, out);
}

// Round 12
// 1287.566 us; speedup vs baseline: 5.5606x; 5.5606x over previous
//
#include <hip/hip_runtime.h>
#include <cstdint>

// ---------------------------------------------------------------------------
// SA_Layer_PN2: centers + 32-NN + (gather,concat) -> 3x [1x1conv -> BN -> ReLU]
// -> max over k.  f32 math, bf16 activation storage.
// R11 lesson: FULL unroll of the c4 loop around acc[32]+pk[8] -> VGPR 256 +
// 14GB scratch spill (6.4ms). Unroll policy, not the hoist, was the bug.
// R12: k_l3 v5 = k_l2's proven skeleton (pk[8] hoist, unroll-1 over r=8,
// unrolled h2), epilogue unchanged from the 531us v3. knn FROZEN (256,1).
// ---------------------------------------------------------------------------

constexpr int B_ = 8;
constexpr int N_ = 8192;
constexpr int M_ = 2048;
constexpr int K_ = 32;
constexpr float NTINV = 1.0f / 524288.0f;   // 1 / (B*M*K)
constexpr float BN_EPS = 1e-5f;

// workspace layout (bytes)
constexpr size_t OFF_KNN   = 0;             // int32 [B*M*K]          2,097,152
constexpr size_t OFF_FEATB = 2097152;       // bf16 [B*N*64]          8,388,608
constexpr size_t OFF_MAXZ  = 2097152;       // f32 [16384*128] ALIASES featB (dead after k_l1)
constexpr size_t OFF_XYZ4  = 10485760;      // f32x4 [B*N]            2,097,152
constexpr size_t OFF_XN    = 12582912;      // f32 [B*N]                262,144
constexpr size_t OFF_WT1   = 12845056;      // f32 [67*64]
constexpr size_t OFF_WT2   = 12862208;      // f32 [64*64]
constexpr size_t OFF_WT3   = 12878592;      // f32 [64*128]
constexpr size_t OFF_GST   = 12911360;      // f32 [512]
constexpr size_t OFF_SS1   = 12913408;      // f32 [128]
constexpr size_t OFF_SS2   = 12913920;      // f32 [128]
constexpr size_t OFF_Z     = 12914432;      // bf16 [524288*64]      67,108,864
constexpr size_t WS_NEED   = 80023296;      // ~80 MB total

// ---- bf16 helpers (RNE) ----------------------------------------------------
__device__ __forceinline__ unsigned int pack_bf2(float a, float b) {
  unsigned int ua = __float_as_uint(a);
  unsigned int ub = __float_as_uint(b);
  ua = ua + 0x7FFFu + ((ua >> 16) & 1u);
  ub = ub + 0x7FFFu + ((ub >> 16) & 1u);
  return (ua >> 16) | (ub & 0xFFFF0000u);
}
__device__ __forceinline__ float bf_lo(unsigned int u) { return __uint_as_float(u << 16); }
__device__ __forceinline__ float bf_hi(unsigned int u) { return __uint_as_float(u & 0xFFFF0000u); }

// ---------------------------------------------------------------------------
// k_prep: featB (bf16) pack, xyz4 pad, xyz norms, weight transposes, centers
// ---------------------------------------------------------------------------
__global__ __launch_bounds__(256) void k_prep(
    const float* __restrict__ xyz, const float* __restrict__ feat,
    const float* __restrict__ W1, const float* __restrict__ W2,
    const float* __restrict__ W3,
    unsigned short* __restrict__ featB, float* __restrict__ xyz4,
    float* __restrict__ xn,
    float* __restrict__ wt1, float* __restrict__ wt2, float* __restrict__ wt3,
    float* __restrict__ cent_out)
{
  const int id = blockIdx.x * 256 + threadIdx.x;
  if (id < B_ * N_) {
    const int b = id >> 13;
    const int n = id & (N_ - 1);
    const float* pp = xyz + id * 3;
    const float x = pp[0], y = pp[1], z = pp[2];
    xn[id] = x * x + y * y + z * z;
    float4* x4 = (float4*)xyz4;
    x4[id] = make_float4(x, y, z, 0.0f);
    const float* fsrc = feat + b * 64 * N_ + n;
    unsigned short* fdst = featB + (size_t)id * 64;
#pragma unroll
    for (int c8 = 0; c8 < 8; ++c8) {
      uint4 v;
      v.x = pack_bf2(fsrc[(c8 * 8 + 0) * N_], fsrc[(c8 * 8 + 1) * N_]);
      v.y = pack_bf2(fsrc[(c8 * 8 + 2) * N_], fsrc[(c8 * 8 + 3) * N_]);
      v.z = pack_bf2(fsrc[(c8 * 8 + 4) * N_], fsrc[(c8 * 8 + 5) * N_]);
      v.w = pack_bf2(fsrc[(c8 * 8 + 6) * N_], fsrc[(c8 * 8 + 7) * N_]);
      *(uint4*)(fdst + c8 * 8) = v;
    }
  } else if (id < B_ * N_ + B_ * M_) {
    const int idx = id - B_ * N_;
    const int b = idx >> 11;
    const int m = idx & (M_ - 1);
    const int ic = (int)(((long long)m * (N_ - 1)) / (M_ - 1));
    const float* cp = xyz + (b * N_ + ic) * 3;
    float* dst = cent_out + idx * 3;
    dst[0] = cp[0]; dst[1] = cp[1]; dst[2] = cp[2];
  } else if (id < 81920 + 4288) {
    const int i = id - 81920;
    const int c = i >> 6, o = i & 63;
    wt1[i] = W1[o * 67 + c];
  } else if (id < 86208 + 4096) {
    const int i = id - 86208;
    const int c = i >> 6, o = i & 63;
    wt2[c * 64 + o] = W2[o * 64 + c];
  } else if (id < 90304 + 8192) {
    const int i = id - 90304;
    const int c = i >> 7, o = i & 127;
    wt3[c * 128 + o] = W3[o * 64 + c];
  }
}

// ---------------------------------------------------------------------------
// k_knn: R2-passing source + (256,1) despill — FROZEN (R10 verified bits
// preserved, no scratch). Do not touch.
// ---------------------------------------------------------------------------
__global__ __launch_bounds__(256, 1) void k_knn(
    const float* __restrict__ xyz, const float* __restrict__ xn,
    int* __restrict__ knn)
{
  constexpr int CAP = 2048;
  __shared__ unsigned int hist[512];
  __shared__ unsigned long long keys[CAP];
  __shared__ int sh_cnt, sh_B, wsum[4];

  const int t = threadIdx.x;
  const int bid = blockIdx.x;
  const int b = bid >> 9;
  const int m0 = (bid & 511) * 4;

  float cx[4], cy[4], cz[4], cb[4];
#pragma unroll
  for (int s = 0; s < 4; ++s) {
    const int m = m0 + s;
    const int ic = (int)(((long long)m * (N_ - 1)) / (M_ - 1));
    const float* cp = xyz + (b * N_ + ic) * 3;
    cx[s] = cp[0]; cy[s] = cp[1]; cz[s] = cp[2];
    cb[s] = cx[s] * cx[s] + cy[s] * cy[s] + cz[s] * cz[s];
  }

  unsigned int u[4][32];
  unsigned int umin[4] = {0xFFFFFFFFu, 0xFFFFFFFFu, 0xFFFFFFFFu, 0xFFFFFFFFu};
#pragma unroll
  for (int j = 0; j < 32; ++j) {
    const int n = t + 256 * j;
    const float* pp = xyz + (b * N_ + n) * 3;
    const float x = pp[0], y = pp[1], z = pp[2];
    const float xv = xn[b * N_ + n];
#pragma unroll
    for (int s = 0; s < 4; ++s) {
      const float dot = cx[s] * x + cy[s] * y + cz[s] * z;
      const float d2 = (cb[s] + xv) - 2.0f * dot;      // same formula as ref
      const unsigned int bits = __float_as_uint(d2);
      const unsigned int key = bits ^ ((unsigned int)((int)bits >> 31) | 0x80000000u);
      u[s][j] = key;
      umin[s] = umin[s] < key ? umin[s] : key;
    }
  }

  const int row_base = (b * M_ + m0) * K_;
#pragma unroll 1
  for (int s = 0; s < 4; ++s) {
    int* row = knn + row_base + s * K_;
    __syncthreads();
    hist[t] = 0; hist[t + 256] = 0;
    if (t == 0) sh_cnt = 0;
    __syncthreads();
    atomicAdd(&hist[umin[s] >> 23], 1u);
    __syncthreads();
    if (t < 64) {
      unsigned int h8[8]; unsigned int sum = 0;
#pragma unroll
      for (int q = 0; q < 8; ++q) { h8[q] = hist[t * 8 + q]; sum += h8[q]; }
      unsigned int incl = sum;
#pragma unroll
      for (int off = 1; off < 64; off <<= 1) {
        unsigned int w = __shfl_up(incl, off);
        if (t >= off) incl += w;
      }
      unsigned int run = incl - sum;
      int Bq = -1;
#pragma unroll
      for (int q = 0; q < 8; ++q) { run += h8[q]; if (Bq < 0 && run >= 33) Bq = t * 8 + q; }
      unsigned long long bal = __ballot(Bq >= 0);
      int src = __ffsll((long long)bal) - 1;
      int Bsel = __shfl(Bq, src);
      if (t == 0) sh_B = Bsel;
    }
    __syncthreads();
    const unsigned int Bbin = (unsigned int)sh_B;

    int cc = 0;
#pragma unroll
    for (int j = 0; j < 32; ++j) cc += ((u[s][j] >> 23) <= Bbin) ? 1 : 0;
#pragma unroll
    for (int off = 1; off < 64; off <<= 1) cc += __shfl_xor(cc, off);
    if ((t & 63) == 0) wsum[t >> 6] = cc;
    __syncthreads();
    const int total = wsum[0] + wsum[1] + wsum[2] + wsum[3];

    if (total <= CAP) {
#pragma unroll
      for (int j = 0; j < 32; ++j) {
        if ((u[s][j] >> 23) <= Bbin) {
          const int pos = atomicAdd(&sh_cnt, 1);
          keys[pos] = ((unsigned long long)u[s][j] << 32) | (unsigned int)(t + 256 * j);
        }
      }
      __syncthreads();
      const int C = sh_cnt;
      for (int i = t; i < C; i += 256) {
        const unsigned long long k = keys[i];
        int r = 0;
        for (int q = 0; q < C; ++q) r += (keys[q] < k) ? 1 : 0;
        if (r < K_) row[r] = (int)(k & 0xFFFFFFFFull);
      }
      __syncthreads();
    } else {
      // slow exact fallback (practically never taken)
      unsigned int uu[32];
#pragma unroll
      for (int j = 0; j < 32; ++j) uu[j] = u[s][j];
#pragma unroll 1
      for (int r = 0; r < K_; ++r) {
        unsigned long long best = 0xFFFFFFFFFFFFFFFFull;
#pragma unroll
        for (int j = 0; j < 32; ++j) {
          unsigned long long k = ((unsigned long long)uu[j] << 32) | (unsigned int)(t + 256 * j);
          best = (k < best) ? k : best;
        }
#pragma unroll
        for (int off = 1; off < 64; off <<= 1) {
          unsigned long long o = __shfl_xor(best, off);
          best = (o < best) ? o : best;
        }
        if ((t & 63) == 0) keys[t >> 6] = best;
        __syncthreads();
        unsigned long long b01 = keys[0] < keys[1] ? keys[0] : keys[1];
        unsigned long long b23 = keys[2] < keys[3] ? keys[2] : keys[3];
        best = b01 < b23 ? b01 : b23;
        if (t == 0) row[r] = (int)(best & 0xFFFFFFFFull);
        const int n_match = (int)(best & 0xFFFFFFFFull);
#pragma unroll
        for (int j = 0; j < 32; ++j)
          if ((t + 256 * j) == n_match) uu[j] = 0xFFFFFFFFu;
        __syncthreads();
      }
    }
  }
}

// ---------------------------------------------------------------------------
// k_l1 v4: cooperative LDS staging of gathered bf16 rows (coalesced 128B
// segments, 8 lanes/row), then 1 pt/lane GEMM 67->64 in two 32-ch chunks.
// ---------------------------------------------------------------------------
__global__ __launch_bounds__(256) void k_l1(
    const float* __restrict__ xyz4, const unsigned short* __restrict__ featB,
    const int* __restrict__ knn, const float* __restrict__ centers,
    const float* __restrict__ Wt, const float* __restrict__ bias,
    unsigned short* __restrict__ zout)
{
  __shared__ unsigned short rows[256 * 72];   // 144B row stride, 36.9 KB
  const int t = threadIdx.x;
  const int p0 = blockIdx.x * 256;            // 2048 blocks

  // stage: 8 rounds x 32 rows; thread t -> row 32k+(t>>3), 16B chunk (t&7)
  const int rb = t >> 3, ci = t & 7;
#pragma unroll
  for (int k = 0; k < 8; ++k) {
    const int ri = k * 32 + rb;
    const int pr = p0 + ri;
    const int bb = pr >> 16;
    const int nnr = knn[pr];
    const uint4* src = (const uint4*)(featB + ((size_t)bb * N_ + nnr) * 64);
    *(uint4*)&rows[ri * 72 + ci * 8] = src[ci];
  }

  const int p = p0 + t;
  const int b = p >> 16;
  const int m = (p & 65535) >> 5;
  const int nn = knn[p];
  const float4 pv = ((const float4*)xyz4)[b * N_ + nn];
  const float* cp = centers + (b * M_ + m) * 3;
  const float l0 = pv.x - cp[0];
  const float l1v = pv.y - cp[1];
  const float l2v = pv.z - cp[2];
  __syncthreads();

  const unsigned short* myrow = rows + t * 72;
  unsigned short* zp = zout + (size_t)p * 64;

#pragma unroll 1
  for (int chunk = 0; chunk < 2; ++chunk) {
    const int ob = chunk * 32;
    float acc[32];
    const float* w0 = Wt + ob;
    const float* w1 = Wt + 64 + ob;
    const float* w2 = Wt + 128 + ob;
#pragma unroll
    for (int i = 0; i < 32; ++i)
      acc[i] = fmaf(l0, w0[i], fmaf(l1v, w1[i], fmaf(l2v, w2[i], bias[ob + i])));

#pragma unroll 1
    for (int r = 0; r < 8; ++r) {
      const uint4 v = *(const uint4*)(myrow + r * 8);
      const unsigned int uu[4] = {v.x, v.y, v.z, v.w};
#pragma unroll
      for (int h2 = 0; h2 < 4; ++h2) {
        const int c = 3 + r * 8 + h2 * 2;
        const float f0 = bf_lo(uu[h2]);
        const float f1 = bf_hi(uu[h2]);
        const float* wa = Wt + c * 64 + ob;
        const float* wb = wa + 64;
#pragma unroll
        for (int i = 0; i < 32; ++i)
          acc[i] = fmaf(f0, wa[i], fmaf(f1, wb[i], acc[i]));
      }
    }

    uint4* zo = (uint4*)(zp + ob);
#pragma unroll
    for (int r = 0; r < 4; ++r) {
      uint4 o4;
      o4.x = pack_bf2(acc[r * 8 + 0], acc[r * 8 + 1]);
      o4.y = pack_bf2(acc[r * 8 + 2], acc[r * 8 + 3]);
      o4.z = pack_bf2(acc[r * 8 + 4], acc[r * 8 + 5]);
      o4.w = pack_bf2(acc[r * 8 + 6], acc[r * 8 + 7]);
      zo[r] = o4;
    }
  }
}

// ---------------------------------------------------------------------------
// k_l2: IN-PLACE GEMM 64->64, one point per lane, output in two 32-ch chunks.
// ---------------------------------------------------------------------------
__global__ __launch_bounds__(256) void k_l2(
    unsigned short* __restrict__ z, const float* __restrict__ Wt,
    const float* __restrict__ bias, const float* __restrict__ ss)
{
  const int p = blockIdx.x * 256 + threadIdx.x;
  unsigned short* zp = z + (size_t)p * 64;
  const uint4* zv = (const uint4*)zp;

  uint4 pk[8];
#pragma unroll
  for (int r = 0; r < 8; ++r) pk[r] = zv[r];

#pragma unroll 1
  for (int chunk = 0; chunk < 2; ++chunk) {
    const int ob = chunk * 32;
    float acc[32];
#pragma unroll
    for (int i = 0; i < 32; ++i) acc[i] = bias[ob + i];

#pragma unroll 1
    for (int r = 0; r < 8; ++r) {
      const unsigned int uu[4] = {pk[r].x, pk[r].y, pk[r].z, pk[r].w};
#pragma unroll
      for (int h2 = 0; h2 < 4; ++h2) {
        const int c0 = r * 8 + h2 * 2;
        const float f0 = fmaxf(0.0f, fmaf(bf_lo(uu[h2]), ss[c0], ss[64 + c0]));
        const float f1 = fmaxf(0.0f, fmaf(bf_hi(uu[h2]), ss[c0 + 1], ss[64 + c0 + 1]));
        const float* w0 = Wt + c0 * 64 + ob;
        const float* w1 = w0 + 64;
#pragma unroll
        for (int i = 0; i < 32; ++i)
          acc[i] = fmaf(f0, w0[i], fmaf(f1, w1[i], acc[i]));
      }
    }

    uint4* zo = (uint4*)(zp + ob);
#pragma unroll
    for (int r = 0; r < 4; ++r) {
      uint4 o4;
      o4.x = pack_bf2(acc[r * 8 + 0], acc[r * 8 + 1]);
      o4.y = pack_bf2(acc[r * 8 + 2], acc[r * 8 + 3]);
      o4.z = pack_bf2(acc[r * 8 + 4], acc[r * 8 + 5]);
      o4.w = pack_bf2(acc[r * 8 + 6], acc[r * 8 + 7]);
      zo[r] = o4;
    }
  }
}

// ---------------------------------------------------------------------------
// k_stats2: scan z (bf16), per-channel sum/sumsq -> gstats[0..127].
// ---------------------------------------------------------------------------
__global__ __launch_bounds__(256) void k_stats2(
    const unsigned short* __restrict__ z, float* __restrict__ gstats)
{
  __shared__ float ls[128];
  const int t = threadIdx.x;
  const int lane = t & 63;
  const int cq = t & 3;
  if (t < 128) ls[t] = 0.0f;
  __syncthreads();

  float s[16], q[16];
#pragma unroll
  for (int i = 0; i < 16; ++i) { s[i] = 0.0f; q[i] = 0.0f; }

  const int row0 = blockIdx.x * 1024 + (t >> 2);   // 512 blocks
#pragma unroll 1
  for (int it = 0; it < 16; ++it) {
    const int p = row0 + it * 64;
    const uint4* zp = (const uint4*)(z + (size_t)p * 64 + cq * 16);
    const uint4 v0 = zp[0];
    const uint4 v1 = zp[1];
    const unsigned int uu[8] = {v0.x, v0.y, v0.z, v0.w, v1.x, v1.y, v1.z, v1.w};
#pragma unroll
    for (int h2 = 0; h2 < 8; ++h2) {
      const float f0 = bf_lo(uu[h2]);
      const float f1 = bf_hi(uu[h2]);
      s[h2 * 2] += f0;     q[h2 * 2] = fmaf(f0, f0, q[h2 * 2]);
      s[h2 * 2 + 1] += f1; q[h2 * 2 + 1] = fmaf(f1, f1, q[h2 * 2 + 1]);
    }
  }

#pragma unroll
  for (int i = 0; i < 16; ++i) {
    float sv = s[i], qv = q[i];
#pragma unroll
    for (int off = 4; off < 64; off <<= 1) {
      sv += __shfl_xor(sv, off);
      qv += __shfl_xor(qv, off);
    }
    if (lane < 4) {
      atomicAdd(&ls[cq * 16 + i], sv);
      atomicAdd(&ls[64 + cq * 16 + i], qv);
    }
  }
  __syncthreads();
  if (t < 128) atomicAdd(&gstats[t], ls[t]);
}

// ---------------------------------------------------------------------------
// k_l3 v5: GEMM 64->128 with k_l2's proven skeleton (pk[8] hoist, unroll-1
// over r=8, unrolled h2=4, 2 channels per step). Epilogue = v3 (LDS
// transpose, shuffle-free sequential reductions).
// ---------------------------------------------------------------------------
__global__ __launch_bounds__(256) void k_l3(
    const unsigned short* __restrict__ zin, const float* __restrict__ Wt,
    const float* __restrict__ bias, const float* __restrict__ ss,
    const float* __restrict__ gvec, float* __restrict__ maxz,
    float* __restrict__ gstats)
{
  constexpr int PITCH = 129;                 // odd pitch: 2-way (free) banks
  __shared__ float tile[64 * PITCH];         // 33.0 KB
  __shared__ float ls[256];
  const int t = threadIdx.x;
  const int lane = t & 63;
  const int wv = t >> 6;
  const int ob = wv * 32;
  const int p0 = blockIdx.x * 128;           // 4096 blocks, 128 points each

  const int ch = t & 127;                    // epilogue mapping
  const int bmg = t >> 7;                    // 0..1 (which 32-pt group)
  const bool um = (gvec[ch] >= 0.0f);
  float s_acc = 0.0f, q_acc = 0.0f;
  ls[t] = 0.0f;

#pragma unroll 1
  for (int g = 0; g < 2; ++g) {
    const int pbase = p0 + g * 64 + lane;
    const uint4* zv = (const uint4*)(zin + (size_t)pbase * 64);

    uint4 pk[8];
#pragma unroll
    for (int r = 0; r < 8; ++r) pk[r] = zv[r];

    float acc[32];
#pragma unroll
    for (int i = 0; i < 32; ++i) acc[i] = 0.0f;

#pragma unroll 1
    for (int r = 0; r < 8; ++r) {
      const unsigned int uu[4] = {pk[r].x, pk[r].y, pk[r].z, pk[r].w};
#pragma unroll
      for (int h2 = 0; h2 < 4; ++h2) {
        const int c0 = r * 8 + h2 * 2;
        const float f0 = fmaxf(0.0f, fmaf(bf_lo(uu[h2]), ss[c0], ss[64 + c0]));
        const float f1 = fmaxf(0.0f, fmaf(bf_hi(uu[h2]), ss[c0 + 1], ss[64 + c0 + 1]));
        const float* w0 = Wt + c0 * 128 + ob;
        const float* w1 = w0 + 128;
#pragma unroll
        for (int i = 0; i < 32; ++i)
          acc[i] = fmaf(f0, w0[i], fmaf(f1, w1[i], acc[i]));
      }
    }

    __syncthreads();   // previous read phase done (and ls init on g=0)
    float* tp = tile + lane * PITCH + ob;
#pragma unroll
    for (int i = 0; i < 32; ++i) tp[i] = acc[i] + bias[ob + i];
    __syncthreads();

    // read phase: thread -> (bmg, ch); 32 sequential points, no shuffles
    const float* rp = tile + (bmg * 32) * PITCH + ch;
    float x = rp[0];
    float sl = 0.0f, ql = 0.0f;
#pragma unroll
    for (int j = 0; j < 32; ++j) {
      const float v = rp[j * PITCH];
      sl += v;
      ql = fmaf(v, v, ql);
      x = um ? fmaxf(x, v) : fminf(x, v);
    }
    s_acc += sl;
    q_acc += ql;
    const int bm = blockIdx.x * 4 + g * 2 + bmg;
    maxz[(size_t)bm * 128 + ch] = x;
  }

  atomicAdd(&ls[ch], s_acc);
  atomicAdd(&ls[128 + ch], q_acc);
  __syncthreads();
  atomicAdd(&gstats[t], ls[t]);              // 256 slots: s[0..127], q[128..255]
}

// ---------------------------------------------------------------------------
// k_bnfin: scale = g*rsqrt(var+eps), shift = be - mu*scale  (64 channels)
// ---------------------------------------------------------------------------
__global__ void k_bnfin(const float* __restrict__ gstats,
                        const float* __restrict__ g, const float* __restrict__ be,
                        float* __restrict__ ss)
{
  const int t = threadIdx.x;  // 64
  const float s = gstats[t], q = gstats[64 + t];
  const float mu = s * NTINV;
  const float var = q * NTINV - mu * mu;
  const float scale = g[t] * rsqrtf(var + BN_EPS);
  ss[t] = scale;
  ss[64 + t] = be[t] - mu * scale;
}

// ---------------------------------------------------------------------------
// k_final: finalize BN3, apply to pooled extremes, ReLU, transpose to (B,128,M)
// gstats layout here: s at [ch], q at [128+ch].
// ---------------------------------------------------------------------------
__global__ __launch_bounds__(256) void k_final(
    const float* __restrict__ maxz, const float* __restrict__ gstats,
    const float* __restrict__ g, const float* __restrict__ be,
    float* __restrict__ out)
{
  __shared__ float sc[128], sh[128];
  __shared__ float tile[128][65];
  const int t = threadIdx.x;
  const int b = blockIdx.x >> 5;
  const int m0 = (blockIdx.x & 31) * 64;
  if (t < 128) {
    const float s = gstats[t], q = gstats[128 + t];
    const float mu = s * NTINV;
    const float var = q * NTINV - mu * mu;
    const float scale = g[t] * rsqrtf(var + BN_EPS);
    sc[t] = scale;
    sh[t] = be[t] - mu * scale;
  }
  __syncthreads();
  const float* src = maxz + (size_t)(b * M_ + m0) * 128;
#pragma unroll
  for (int r = 0; r < 8; ++r) {
    const int flat = r * 1024 + t * 4;
    const int ml = flat >> 7;
    const int o = flat & 127;
    const float4 v = *(const float4*)(src + flat);
    tile[o + 0][ml] = fmaxf(0.0f, fmaf(v.x, sc[o + 0], sh[o + 0]));
    tile[o + 1][ml] = fmaxf(0.0f, fmaf(v.y, sc[o + 1], sh[o + 1]));
    tile[o + 2][ml] = fmaxf(0.0f, fmaf(v.z, sc[o + 2], sh[o + 2]));
    tile[o + 3][ml] = fmaxf(0.0f, fmaf(v.w, sc[o + 3], sh[o + 3]));
  }
  __syncthreads();
  const int o = t >> 1;
  const int mh = (t & 1) * 32;
  float* dst = out + B_ * M_ * 3 + (size_t)(b * 128 + o) * M_ + m0 + mh;
#pragma unroll
  for (int q = 0; q < 8; ++q) {
    float4 v;
    v.x = tile[o][mh + q * 4 + 0];
    v.y = tile[o][mh + q * 4 + 1];
    v.z = tile[o][mh + q * 4 + 2];
    v.w = tile[o][mh + q * 4 + 3];
    *(float4*)(dst + q * 4) = v;
  }
}

// ---------------------------------------------------------------------------
extern "C" void kernel_launch(void* const* d_in, const int* in_sizes, int n_in,
                              void* d_out, int out_size, void* d_ws, size_t ws_size,
                              hipStream_t stream) {
  (void)in_sizes; (void)n_in; (void)out_size;
  if (ws_size < WS_NEED) return;  // safety: fail cleanly, not with a memfault

  const float* xyz = (const float*)d_in[0];
  const float* feat = (const float*)d_in[1];
  const float* W1 = (const float*)d_in[2];
  const float* b1 = (const float*)d_in[3];
  const float* g1 = (const float*)d_in[4];
  const float* be1 = (const float*)d_in[5];
  const float* W2 = (const float*)d_in[6];
  const float* b2 = (const float*)d_in[7];
  const float* g2 = (const float*)d_in[8];
  const float* be2 = (const float*)d_in[9];
  const float* W3 = (const float*)d_in[10];
  const float* b3 = (const float*)d_in[11];
  const float* g3 = (const float*)d_in[12];
  const float* be3 = (const float*)d_in[13];
  float* out = (float*)d_out;
  char* ws = (char*)d_ws;

  int* knn = (int*)(ws + OFF_KNN);
  unsigned short* featB = (unsigned short*)(ws + OFF_FEATB);
  float* maxz = (float*)(ws + OFF_MAXZ);     // aliases featB (dead after k_l1)
  float* xyz4 = (float*)(ws + OFF_XYZ4);
  float* xn = (float*)(ws + OFF_XN);
  float* wt1 = (float*)(ws + OFF_WT1);
  float* wt2 = (float*)(ws + OFF_WT2);
  float* wt3 = (float*)(ws + OFF_WT3);
  float* gst = (float*)(ws + OFF_GST);
  float* ss1 = (float*)(ws + OFF_SS1);
  float* ss2 = (float*)(ws + OFF_SS2);
  unsigned short* z = (unsigned short*)(ws + OFF_Z);

  hipMemsetAsync(gst, 0, 512 * sizeof(float), stream);
  k_prep<<<385, 256, 0, stream>>>(xyz, feat, W1, W2, W3, featB, xyz4, xn,
                                  wt1, wt2, wt3, out);
  k_knn<<<4096, 256, 0, stream>>>(xyz, xn, knn);
  k_l1<<<2048, 256, 0, stream>>>(xyz4, featB, knn, out, wt1, b1, z);
  k_stats2<<<512, 256, 0, stream>>>(z, gst);           // layer-1 stats
  k_bnfin<<<1, 64, 0, stream>>>(gst, g1, be1, ss1);
  k_l2<<<2048, 256, 0, stream>>>(z, wt2, b2, ss1);
  k_stats2<<<512, 256, 0, stream>>>(z, gst + 128);     // layer-2 stats
  k_bnfin<<<1, 64, 0, stream>>>(gst + 128, g2, be2, ss2);
  k_l3<<<4096, 256, 0, stream>>>(z, wt3, b3, ss2, g3, maxz, gst + 256);
  k_final<<<256, 256, 0, stream>>>(maxz, gst + 256, g3, be3, out);
}

// Round 13
// 854.339 us; speedup vs baseline: 8.3804x; 1.5071x over previous
//
#include <hip/hip_runtime.h>
#include <cstdint>

// ---------------------------------------------------------------------------
// SA_Layer_PN2: centers + 32-NN + (gather,concat) -> 3x [1x1conv -> BN -> ReLU]
// -> max over k.  f32 math, bf16 activation storage.
// R12 lesson: VALU-GEMM k_l3 is stuck at ~530-570us (15% VALUBusy, mild
// spill). R13: k_l3 -> MFMA bf16 16x16x32 (wave = 16 pts x 128 ch, 16 mfma),
// BN2+ReLU applied in-register during A-frag build, B prepacked in fragment
// order by k_prep. Epilogue = v3 LDS transpose (PITCH 130). knn FROZEN.
// ---------------------------------------------------------------------------

constexpr int B_ = 8;
constexpr int N_ = 8192;
constexpr int M_ = 2048;
constexpr int K_ = 32;
constexpr float NTINV = 1.0f / 524288.0f;   // 1 / (B*M*K)
constexpr float BN_EPS = 1e-5f;

// workspace layout (bytes)
constexpr size_t OFF_KNN   = 0;             // int32 [B*M*K]          2,097,152
constexpr size_t OFF_FEATB = 2097152;       // bf16 [B*N*64]          8,388,608
constexpr size_t OFF_MAXZ  = 2097152;       // f32 [16384*128] ALIASES featB (dead after k_l1)
constexpr size_t OFF_XYZ4  = 10485760;      // f32x4 [B*N]            2,097,152
constexpr size_t OFF_XN    = 12582912;      // f32 [B*N]                262,144
constexpr size_t OFF_WT1   = 12845056;      // f32 [67*64]
constexpr size_t OFF_WT2   = 12862208;      // f32 [64*64]
constexpr size_t OFF_WT3   = 12878592;      // bf16 frags [8192]         16,384
constexpr size_t OFF_GST   = 12911360;      // f32 [512]
constexpr size_t OFF_SS1   = 12913408;      // f32 [128]
constexpr size_t OFF_SS2   = 12913920;      // f32 [128]
constexpr size_t OFF_Z     = 12914432;      // bf16 [524288*64]      67,108,864
constexpr size_t WS_NEED   = 80023296;      // ~80 MB total

typedef __attribute__((ext_vector_type(8))) short bf16x8;
typedef __attribute__((ext_vector_type(4))) float f32x4;

// ---- bf16 helpers (RNE) ----------------------------------------------------
__device__ __forceinline__ unsigned int pack_bf2(float a, float b) {
  unsigned int ua = __float_as_uint(a);
  unsigned int ub = __float_as_uint(b);
  ua = ua + 0x7FFFu + ((ua >> 16) & 1u);
  ub = ub + 0x7FFFu + ((ub >> 16) & 1u);
  return (ua >> 16) | (ub & 0xFFFF0000u);
}
__device__ __forceinline__ float bf_lo(unsigned int u) { return __uint_as_float(u << 16); }
__device__ __forceinline__ float bf_hi(unsigned int u) { return __uint_as_float(u & 0xFFFF0000u); }

// ---------------------------------------------------------------------------
// k_prep: featB (bf16) pack, xyz4 pad, xyz norms, weight transposes, centers,
// + W3 packed as MFMA B-fragments: frag (ct,ks), lane, j ->
//   B[k=ks*32+quad*8+j][n=ct*16+col] = W3[n][k]
// ---------------------------------------------------------------------------
__global__ __launch_bounds__(256) void k_prep(
    const float* __restrict__ xyz, const float* __restrict__ feat,
    const float* __restrict__ W1, const float* __restrict__ W2,
    const float* __restrict__ W3,
    unsigned short* __restrict__ featB, float* __restrict__ xyz4,
    float* __restrict__ xn,
    float* __restrict__ wt1, float* __restrict__ wt2,
    unsigned short* __restrict__ wt3f,
    float* __restrict__ cent_out)
{
  const int id = blockIdx.x * 256 + threadIdx.x;
  if (id < B_ * N_) {
    const int b = id >> 13;
    const int n = id & (N_ - 1);
    const float* pp = xyz + id * 3;
    const float x = pp[0], y = pp[1], z = pp[2];
    xn[id] = x * x + y * y + z * z;
    float4* x4 = (float4*)xyz4;
    x4[id] = make_float4(x, y, z, 0.0f);
    const float* fsrc = feat + b * 64 * N_ + n;
    unsigned short* fdst = featB + (size_t)id * 64;
#pragma unroll
    for (int c8 = 0; c8 < 8; ++c8) {
      uint4 v;
      v.x = pack_bf2(fsrc[(c8 * 8 + 0) * N_], fsrc[(c8 * 8 + 1) * N_]);
      v.y = pack_bf2(fsrc[(c8 * 8 + 2) * N_], fsrc[(c8 * 8 + 3) * N_]);
      v.z = pack_bf2(fsrc[(c8 * 8 + 4) * N_], fsrc[(c8 * 8 + 5) * N_]);
      v.w = pack_bf2(fsrc[(c8 * 8 + 6) * N_], fsrc[(c8 * 8 + 7) * N_]);
      *(uint4*)(fdst + c8 * 8) = v;
    }
  } else if (id < B_ * N_ + B_ * M_) {
    const int idx = id - B_ * N_;
    const int b = idx >> 11;
    const int m = idx & (M_ - 1);
    const int ic = (int)(((long long)m * (N_ - 1)) / (M_ - 1));
    const float* cp = xyz + (b * N_ + ic) * 3;
    float* dst = cent_out + idx * 3;
    dst[0] = cp[0]; dst[1] = cp[1]; dst[2] = cp[2];
  } else if (id < 81920 + 4288) {
    const int i = id - 81920;
    const int c = i >> 6, o = i & 63;
    wt1[i] = W1[o * 67 + c];
  } else if (id < 86208 + 4096) {
    const int i = id - 86208;
    const int c = i >> 6, o = i & 63;
    wt2[c * 64 + o] = W2[o * 64 + c];
  } else if (id < 90304 + 1024) {
    const int f = id - 90304;           // f = (ct*2+ks)*64 + lane
    const int ct = f >> 7;
    const int ks = (f >> 6) & 1;
    const int lane = f & 63;
    const int quad = lane >> 4;
    const int col = lane & 15;
    const int n = ct * 16 + col;
    const int kb = ks * 32 + quad * 8;
    const float* wr = W3 + n * 64 + kb;
    uint4 v;
    v.x = pack_bf2(wr[0], wr[1]);
    v.y = pack_bf2(wr[2], wr[3]);
    v.z = pack_bf2(wr[4], wr[5]);
    v.w = pack_bf2(wr[6], wr[7]);
    ((uint4*)wt3f)[f] = v;
  }
}

// ---------------------------------------------------------------------------
// k_knn: R2-passing source + (256,1) despill — FROZEN (R10 verified bits
// preserved, no scratch). Do not touch.
// ---------------------------------------------------------------------------
__global__ __launch_bounds__(256, 1) void k_knn(
    const float* __restrict__ xyz, const float* __restrict__ xn,
    int* __restrict__ knn)
{
  constexpr int CAP = 2048;
  __shared__ unsigned int hist[512];
  __shared__ unsigned long long keys[CAP];
  __shared__ int sh_cnt, sh_B, wsum[4];

  const int t = threadIdx.x;
  const int bid = blockIdx.x;
  const int b = bid >> 9;
  const int m0 = (bid & 511) * 4;

  float cx[4], cy[4], cz[4], cb[4];
#pragma unroll
  for (int s = 0; s < 4; ++s) {
    const int m = m0 + s;
    const int ic = (int)(((long long)m * (N_ - 1)) / (M_ - 1));
    const float* cp = xyz + (b * N_ + ic) * 3;
    cx[s] = cp[0]; cy[s] = cp[1]; cz[s] = cp[2];
    cb[s] = cx[s] * cx[s] + cy[s] * cy[s] + cz[s] * cz[s];
  }

  unsigned int u[4][32];
  unsigned int umin[4] = {0xFFFFFFFFu, 0xFFFFFFFFu, 0xFFFFFFFFu, 0xFFFFFFFFu};
#pragma unroll
  for (int j = 0; j < 32; ++j) {
    const int n = t + 256 * j;
    const float* pp = xyz + (b * N_ + n) * 3;
    const float x = pp[0], y = pp[1], z = pp[2];
    const float xv = xn[b * N_ + n];
#pragma unroll
    for (int s = 0; s < 4; ++s) {
      const float dot = cx[s] * x + cy[s] * y + cz[s] * z;
      const float d2 = (cb[s] + xv) - 2.0f * dot;      // same formula as ref
      const unsigned int bits = __float_as_uint(d2);
      const unsigned int key = bits ^ ((unsigned int)((int)bits >> 31) | 0x80000000u);
      u[s][j] = key;
      umin[s] = umin[s] < key ? umin[s] : key;
    }
  }

  const int row_base = (b * M_ + m0) * K_;
#pragma unroll 1
  for (int s = 0; s < 4; ++s) {
    int* row = knn + row_base + s * K_;
    __syncthreads();
    hist[t] = 0; hist[t + 256] = 0;
    if (t == 0) sh_cnt = 0;
    __syncthreads();
    atomicAdd(&hist[umin[s] >> 23], 1u);
    __syncthreads();
    if (t < 64) {
      unsigned int h8[8]; unsigned int sum = 0;
#pragma unroll
      for (int q = 0; q < 8; ++q) { h8[q] = hist[t * 8 + q]; sum += h8[q]; }
      unsigned int incl = sum;
#pragma unroll
      for (int off = 1; off < 64; off <<= 1) {
        unsigned int w = __shfl_up(incl, off);
        if (t >= off) incl += w;
      }
      unsigned int run = incl - sum;
      int Bq = -1;
#pragma unroll
      for (int q = 0; q < 8; ++q) { run += h8[q]; if (Bq < 0 && run >= 33) Bq = t * 8 + q; }
      unsigned long long bal = __ballot(Bq >= 0);
      int src = __ffsll((long long)bal) - 1;
      int Bsel = __shfl(Bq, src);
      if (t == 0) sh_B = Bsel;
    }
    __syncthreads();
    const unsigned int Bbin = (unsigned int)sh_B;

    int cc = 0;
#pragma unroll
    for (int j = 0; j < 32; ++j) cc += ((u[s][j] >> 23) <= Bbin) ? 1 : 0;
#pragma unroll
    for (int off = 1; off < 64; off <<= 1) cc += __shfl_xor(cc, off);
    if ((t & 63) == 0) wsum[t >> 6] = cc;
    __syncthreads();
    const int total = wsum[0] + wsum[1] + wsum[2] + wsum[3];

    if (total <= CAP) {
#pragma unroll
      for (int j = 0; j < 32; ++j) {
        if ((u[s][j] >> 23) <= Bbin) {
          const int pos = atomicAdd(&sh_cnt, 1);
          keys[pos] = ((unsigned long long)u[s][j] << 32) | (unsigned int)(t + 256 * j);
        }
      }
      __syncthreads();
      const int C = sh_cnt;
      for (int i = t; i < C; i += 256) {
        const unsigned long long k = keys[i];
        int r = 0;
        for (int q = 0; q < C; ++q) r += (keys[q] < k) ? 1 : 0;
        if (r < K_) row[r] = (int)(k & 0xFFFFFFFFull);
      }
      __syncthreads();
    } else {
      // slow exact fallback (practically never taken)
      unsigned int uu[32];
#pragma unroll
      for (int j = 0; j < 32; ++j) uu[j] = u[s][j];
#pragma unroll 1
      for (int r = 0; r < K_; ++r) {
        unsigned long long best = 0xFFFFFFFFFFFFFFFFull;
#pragma unroll
        for (int j = 0; j < 32; ++j) {
          unsigned long long k = ((unsigned long long)uu[j] << 32) | (unsigned int)(t + 256 * j);
          best = (k < best) ? k : best;
        }
#pragma unroll
        for (int off = 1; off < 64; off <<= 1) {
          unsigned long long o = __shfl_xor(best, off);
          best = (o < best) ? o : best;
        }
        if ((t & 63) == 0) keys[t >> 6] = best;
        __syncthreads();
        unsigned long long b01 = keys[0] < keys[1] ? keys[0] : keys[1];
        unsigned long long b23 = keys[2] < keys[3] ? keys[2] : keys[3];
        best = b01 < b23 ? b01 : b23;
        if (t == 0) row[r] = (int)(best & 0xFFFFFFFFull);
        const int n_match = (int)(best & 0xFFFFFFFFull);
#pragma unroll
        for (int j = 0; j < 32; ++j)
          if ((t + 256 * j) == n_match) uu[j] = 0xFFFFFFFFu;
        __syncthreads();
      }
    }
  }
}

// ---------------------------------------------------------------------------
// k_l1 v4: cooperative LDS staging of gathered bf16 rows (coalesced 128B
// segments, 8 lanes/row), then 1 pt/lane GEMM 67->64 in two 32-ch chunks.
// ---------------------------------------------------------------------------
__global__ __launch_bounds__(256) void k_l1(
    const float* __restrict__ xyz4, const unsigned short* __restrict__ featB,
    const int* __restrict__ knn, const float* __restrict__ centers,
    const float* __restrict__ Wt, const float* __restrict__ bias,
    unsigned short* __restrict__ zout)
{
  __shared__ unsigned short rows[256 * 72];   // 144B row stride, 36.9 KB
  const int t = threadIdx.x;
  const int p0 = blockIdx.x * 256;            // 2048 blocks

  // stage: 8 rounds x 32 rows; thread t -> row 32k+(t>>3), 16B chunk (t&7)
  const int rb = t >> 3, ci = t & 7;
#pragma unroll
  for (int k = 0; k < 8; ++k) {
    const int ri = k * 32 + rb;
    const int pr = p0 + ri;
    const int bb = pr >> 16;
    const int nnr = knn[pr];
    const uint4* src = (const uint4*)(featB + ((size_t)bb * N_ + nnr) * 64);
    *(uint4*)&rows[ri * 72 + ci * 8] = src[ci];
  }

  const int p = p0 + t;
  const int b = p >> 16;
  const int m = (p & 65535) >> 5;
  const int nn = knn[p];
  const float4 pv = ((const float4*)xyz4)[b * N_ + nn];
  const float* cp = centers + (b * M_ + m) * 3;
  const float l0 = pv.x - cp[0];
  const float l1v = pv.y - cp[1];
  const float l2v = pv.z - cp[2];
  __syncthreads();

  const unsigned short* myrow = rows + t * 72;
  unsigned short* zp = zout + (size_t)p * 64;

#pragma unroll 1
  for (int chunk = 0; chunk < 2; ++chunk) {
    const int ob = chunk * 32;
    float acc[32];
    const float* w0 = Wt + ob;
    const float* w1 = Wt + 64 + ob;
    const float* w2 = Wt + 128 + ob;
#pragma unroll
    for (int i = 0; i < 32; ++i)
      acc[i] = fmaf(l0, w0[i], fmaf(l1v, w1[i], fmaf(l2v, w2[i], bias[ob + i])));

#pragma unroll 1
    for (int r = 0; r < 8; ++r) {
      const uint4 v = *(const uint4*)(myrow + r * 8);
      const unsigned int uu[4] = {v.x, v.y, v.z, v.w};
#pragma unroll
      for (int h2 = 0; h2 < 4; ++h2) {
        const int c = 3 + r * 8 + h2 * 2;
        const float f0 = bf_lo(uu[h2]);
        const float f1 = bf_hi(uu[h2]);
        const float* wa = Wt + c * 64 + ob;
        const float* wb = wa + 64;
#pragma unroll
        for (int i = 0; i < 32; ++i)
          acc[i] = fmaf(f0, wa[i], fmaf(f1, wb[i], acc[i]));
      }
    }

    uint4* zo = (uint4*)(zp + ob);
#pragma unroll
    for (int r = 0; r < 4; ++r) {
      uint4 o4;
      o4.x = pack_bf2(acc[r * 8 + 0], acc[r * 8 + 1]);
      o4.y = pack_bf2(acc[r * 8 + 2], acc[r * 8 + 3]);
      o4.z = pack_bf2(acc[r * 8 + 4], acc[r * 8 + 5]);
      o4.w = pack_bf2(acc[r * 8 + 6], acc[r * 8 + 7]);
      zo[r] = o4;
    }
  }
}

// ---------------------------------------------------------------------------
// k_l2: IN-PLACE GEMM 64->64, one point per lane, output in two 32-ch chunks.
// ---------------------------------------------------------------------------
__global__ __launch_bounds__(256) void k_l2(
    unsigned short* __restrict__ z, const float* __restrict__ Wt,
    const float* __restrict__ bias, const float* __restrict__ ss)
{
  const int p = blockIdx.x * 256 + threadIdx.x;
  unsigned short* zp = z + (size_t)p * 64;
  const uint4* zv = (const uint4*)zp;

  uint4 pk[8];
#pragma unroll
  for (int r = 0; r < 8; ++r) pk[r] = zv[r];

#pragma unroll 1
  for (int chunk = 0; chunk < 2; ++chunk) {
    const int ob = chunk * 32;
    float acc[32];
#pragma unroll
    for (int i = 0; i < 32; ++i) acc[i] = bias[ob + i];

#pragma unroll 1
    for (int r = 0; r < 8; ++r) {
      const unsigned int uu[4] = {pk[r].x, pk[r].y, pk[r].z, pk[r].w};
#pragma unroll
      for (int h2 = 0; h2 < 4; ++h2) {
        const int c0 = r * 8 + h2 * 2;
        const float f0 = fmaxf(0.0f, fmaf(bf_lo(uu[h2]), ss[c0], ss[64 + c0]));
        const float f1 = fmaxf(0.0f, fmaf(bf_hi(uu[h2]), ss[c0 + 1], ss[64 + c0 + 1]));
        const float* w0 = Wt + c0 * 64 + ob;
        const float* w1 = w0 + 64;
#pragma unroll
        for (int i = 0; i < 32; ++i)
          acc[i] = fmaf(f0, w0[i], fmaf(f1, w1[i], acc[i]));
      }
    }

    uint4* zo = (uint4*)(zp + ob);
#pragma unroll
    for (int r = 0; r < 4; ++r) {
      uint4 o4;
      o4.x = pack_bf2(acc[r * 8 + 0], acc[r * 8 + 1]);
      o4.y = pack_bf2(acc[r * 8 + 2], acc[r * 8 + 3]);
      o4.z = pack_bf2(acc[r * 8 + 4], acc[r * 8 + 5]);
      o4.w = pack_bf2(acc[r * 8 + 6], acc[r * 8 + 7]);
      zo[r] = o4;
    }
  }
}

// ---------------------------------------------------------------------------
// k_stats2: scan z (bf16), per-channel sum/sumsq -> gstats[0..127].
// ---------------------------------------------------------------------------
__global__ __launch_bounds__(256) void k_stats2(
    const unsigned short* __restrict__ z, float* __restrict__ gstats)
{
  __shared__ float ls[128];
  const int t = threadIdx.x;
  const int lane = t & 63;
  const int cq = t & 3;
  if (t < 128) ls[t] = 0.0f;
  __syncthreads();

  float s[16], q[16];
#pragma unroll
  for (int i = 0; i < 16; ++i) { s[i] = 0.0f; q[i] = 0.0f; }

  const int row0 = blockIdx.x * 1024 + (t >> 2);   // 512 blocks
#pragma unroll 1
  for (int it = 0; it < 16; ++it) {
    const int p = row0 + it * 64;
    const uint4* zp = (const uint4*)(z + (size_t)p * 64 + cq * 16);
    const uint4 v0 = zp[0];
    const uint4 v1 = zp[1];
    const unsigned int uu[8] = {v0.x, v0.y, v0.z, v0.w, v1.x, v1.y, v1.z, v1.w};
#pragma unroll
    for (int h2 = 0; h2 < 8; ++h2) {
      const float f0 = bf_lo(uu[h2]);
      const float f1 = bf_hi(uu[h2]);
      s[h2 * 2] += f0;     q[h2 * 2] = fmaf(f0, f0, q[h2 * 2]);
      s[h2 * 2 + 1] += f1; q[h2 * 2 + 1] = fmaf(f1, f1, q[h2 * 2 + 1]);
    }
  }

#pragma unroll
  for (int i = 0; i < 16; ++i) {
    float sv = s[i], qv = q[i];
#pragma unroll
    for (int off = 4; off < 64; off <<= 1) {
      sv += __shfl_xor(sv, off);
      qv += __shfl_xor(qv, off);
    }
    if (lane < 4) {
      atomicAdd(&ls[cq * 16 + i], sv);
      atomicAdd(&ls[64 + cq * 16 + i], qv);
    }
  }
  __syncthreads();
  if (t < 128) atomicAdd(&gstats[t], ls[t]);
}

// ---------------------------------------------------------------------------
// k_l3 v6 (MFMA): per g-group of 64 points, wave w computes 16 pts x 128 ch
// via 16x mfma_f32_16x16x32_bf16 (8 ct x 2 ks). A-frag = BN2+ReLU applied
// in-register to z (re-rounded bf16). B-frag = prepacked wt3f. D (col=lane&15,
// row=quad*4+reg) + bias -> LDS tile; epilogue = v3 sequential reductions.
// ---------------------------------------------------------------------------
__global__ __launch_bounds__(256) void k_l3(
    const unsigned short* __restrict__ zin,
    const unsigned short* __restrict__ wf,
    const float* __restrict__ bias, const float* __restrict__ ss,
    const float* __restrict__ gvec, float* __restrict__ maxz,
    float* __restrict__ gstats)
{
  constexpr int PITCH = 130;                 // 2-way (free) bank pattern
  __shared__ float tile[64 * PITCH];         // 33.3 KB
  __shared__ float ls[256];
  const int t = threadIdx.x;
  const int lane = t & 63;
  const int w = t >> 6;
  const int quad = lane >> 4;
  const int col = lane & 15;
  const int p0 = blockIdx.x * 128;           // 4096 blocks, 128 points each

  const int ch = t & 127;                    // epilogue mapping
  const int bmg = t >> 7;                    // 0..1 (which 32-pt group)
  const bool um = (gvec[ch] >= 0.0f);
  float s_acc = 0.0f, q_acc = 0.0f;
  ls[t] = 0.0f;

  const float4* scv = (const float4*)ss;
  const float4* shv = (const float4*)(ss + 64);

#pragma unroll 1
  for (int g = 0; g < 2; ++g) {
    const int prow = p0 + g * 64 + w * 16 + col;   // this lane's A-row point

    // build A-fragments (ks=0,1): load 16B of z, BN2+ReLU, repack bf16
    bf16x8 afr[2];
#pragma unroll
    for (int ks = 0; ks < 2; ++ks) {
      const int k0 = ks * 32 + quad * 8;
      const uint4 raw = *(const uint4*)(zin + (size_t)prow * 64 + k0);
      const float4 s0 = scv[k0 >> 2], s1 = scv[(k0 >> 2) + 1];
      const float4 h0 = shv[k0 >> 2], h1 = shv[(k0 >> 2) + 1];
      const float f0 = fmaxf(0.0f, fmaf(bf_lo(raw.x), s0.x, h0.x));
      const float f1 = fmaxf(0.0f, fmaf(bf_hi(raw.x), s0.y, h0.y));
      const float f2 = fmaxf(0.0f, fmaf(bf_lo(raw.y), s0.z, h0.z));
      const float f3 = fmaxf(0.0f, fmaf(bf_hi(raw.y), s0.w, h0.w));
      const float f4 = fmaxf(0.0f, fmaf(bf_lo(raw.z), s1.x, h1.x));
      const float f5 = fmaxf(0.0f, fmaf(bf_hi(raw.z), s1.y, h1.y));
      const float f6 = fmaxf(0.0f, fmaf(bf_lo(raw.w), s1.z, h1.z));
      const float f7 = fmaxf(0.0f, fmaf(bf_hi(raw.w), s1.w, h1.w));
      union { uint4 u; bf16x8 v; } cv;
      cv.u.x = pack_bf2(f0, f1);
      cv.u.y = pack_bf2(f2, f3);
      cv.u.z = pack_bf2(f4, f5);
      cv.u.w = pack_bf2(f6, f7);
      afr[ks] = cv.v;
    }

    f32x4 acc[8];
#pragma unroll
    for (int ct = 0; ct < 8; ++ct) acc[ct] = (f32x4){0.f, 0.f, 0.f, 0.f};

#pragma unroll
    for (int ct = 0; ct < 8; ++ct) {
      const bf16x8 b0 = *(const bf16x8*)(wf + ((ct * 2 + 0) * 64 + lane) * 8);
      const bf16x8 b1 = *(const bf16x8*)(wf + ((ct * 2 + 1) * 64 + lane) * 8);
      acc[ct] = __builtin_amdgcn_mfma_f32_16x16x32_bf16(afr[0], b0, acc[ct], 0, 0, 0);
      acc[ct] = __builtin_amdgcn_mfma_f32_16x16x32_bf16(afr[1], b1, acc[ct], 0, 0, 0);
    }

    __syncthreads();   // previous read phase done (and ls init on g=0)
    // D scatter: row = w*16 + quad*4 + reg (local point), col = ct*16+col
#pragma unroll
    for (int ct = 0; ct < 8; ++ct) {
      const int n = ct * 16 + col;
      const float bo = bias[n];
      float* tp = tile + (w * 16 + quad * 4) * PITCH + n;
      tp[0 * PITCH] = acc[ct][0] + bo;
      tp[1 * PITCH] = acc[ct][1] + bo;
      tp[2 * PITCH] = acc[ct][2] + bo;
      tp[3 * PITCH] = acc[ct][3] + bo;
    }
    __syncthreads();

    // read phase: thread -> (bmg, ch); 32 sequential points, no shuffles
    const float* rp = tile + (bmg * 32) * PITCH + ch;
    float x = rp[0];
    float sl = 0.0f, ql = 0.0f;
#pragma unroll
    for (int j = 0; j < 32; ++j) {
      const float v = rp[j * PITCH];
      sl += v;
      ql = fmaf(v, v, ql);
      x = um ? fmaxf(x, v) : fminf(x, v);
    }
    s_acc += sl;
    q_acc += ql;
    const int bm = blockIdx.x * 4 + g * 2 + bmg;
    maxz[(size_t)bm * 128 + ch] = x;
  }

  atomicAdd(&ls[ch], s_acc);
  atomicAdd(&ls[128 + ch], q_acc);
  __syncthreads();
  atomicAdd(&gstats[t], ls[t]);              // 256 slots: s[0..127], q[128..255]
}

// ---------------------------------------------------------------------------
// k_bnfin: scale = g*rsqrt(var+eps), shift = be - mu*scale  (64 channels)
// ---------------------------------------------------------------------------
__global__ void k_bnfin(const float* __restrict__ gstats,
                        const float* __restrict__ g, const float* __restrict__ be,
                        float* __restrict__ ss)
{
  const int t = threadIdx.x;  // 64
  const float s = gstats[t], q = gstats[64 + t];
  const float mu = s * NTINV;
  const float var = q * NTINV - mu * mu;
  const float scale = g[t] * rsqrtf(var + BN_EPS);
  ss[t] = scale;
  ss[64 + t] = be[t] - mu * scale;
}

// ---------------------------------------------------------------------------
// k_final: finalize BN3, apply to pooled extremes, ReLU, transpose to (B,128,M)
// gstats layout here: s at [ch], q at [128+ch].
// ---------------------------------------------------------------------------
__global__ __launch_bounds__(256) void k_final(
    const float* __restrict__ maxz, const float* __restrict__ gstats,
    const float* __restrict__ g, const float* __restrict__ be,
    float* __restrict__ out)
{
  __shared__ float sc[128], sh[128];
  __shared__ float tile[128][65];
  const int t = threadIdx.x;
  const int b = blockIdx.x >> 5;
  const int m0 = (blockIdx.x & 31) * 64;
  if (t < 128) {
    const float s = gstats[t], q = gstats[128 + t];
    const float mu = s * NTINV;
    const float var = q * NTINV - mu * mu;
    const float scale = g[t] * rsqrtf(var + BN_EPS);
    sc[t] = scale;
    sh[t] = be[t] - mu * scale;
  }
  __syncthreads();
  const float* src = maxz + (size_t)(b * M_ + m0) * 128;
#pragma unroll
  for (int r = 0; r < 8; ++r) {
    const int flat = r * 1024 + t * 4;
    const int ml = flat >> 7;
    const int o = flat & 127;
    const float4 v = *(const float4*)(src + flat);
    tile[o + 0][ml] = fmaxf(0.0f, fmaf(v.x, sc[o + 0], sh[o + 0]));
    tile[o + 1][ml] = fmaxf(0.0f, fmaf(v.y, sc[o + 1], sh[o + 1]));
    tile[o + 2][ml] = fmaxf(0.0f, fmaf(v.z, sc[o + 2], sh[o + 2]));
    tile[o + 3][ml] = fmaxf(0.0f, fmaf(v.w, sc[o + 3], sh[o + 3]));
  }
  __syncthreads();
  const int o = t >> 1;
  const int mh = (t & 1) * 32;
  float* dst = out + B_ * M_ * 3 + (size_t)(b * 128 + o) * M_ + m0 + mh;
#pragma unroll
  for (int q = 0; q < 8; ++q) {
    float4 v;
    v.x = tile[o][mh + q * 4 + 0];
    v.y = tile[o][mh + q * 4 + 1];
    v.z = tile[o][mh + q * 4 + 2];
    v.w = tile[o][mh + q * 4 + 3];
    *(float4*)(dst + q * 4) = v;
  }
}

// ---------------------------------------------------------------------------
extern "C" void kernel_launch(void* const* d_in, const int* in_sizes, int n_in,
                              void* d_out, int out_size, void* d_ws, size_t ws_size,
                              hipStream_t stream) {
  (void)in_sizes; (void)n_in; (void)out_size;
  if (ws_size < WS_NEED) return;  // safety: fail cleanly, not with a memfault

  const float* xyz = (const float*)d_in[0];
  const float* feat = (const float*)d_in[1];
  const float* W1 = (const float*)d_in[2];
  const float* b1 = (const float*)d_in[3];
  const float* g1 = (const float*)d_in[4];
  const float* be1 = (const float*)d_in[5];
  const float* W2 = (const float*)d_in[6];
  const float* b2 = (const float*)d_in[7];
  const float* g2 = (const float*)d_in[8];
  const float* be2 = (const float*)d_in[9];
  const float* W3 = (const float*)d_in[10];
  const float* b3 = (const float*)d_in[11];
  const float* g3 = (const float*)d_in[12];
  const float* be3 = (const float*)d_in[13];
  float* out = (float*)d_out;
  char* ws = (char*)d_ws;

  int* knn = (int*)(ws + OFF_KNN);
  unsigned short* featB = (unsigned short*)(ws + OFF_FEATB);
  float* maxz = (float*)(ws + OFF_MAXZ);     // aliases featB (dead after k_l1)
  float* xyz4 = (float*)(ws + OFF_XYZ4);
  float* xn = (float*)(ws + OFF_XN);
  float* wt1 = (float*)(ws + OFF_WT1);
  float* wt2 = (float*)(ws + OFF_WT2);
  unsigned short* wt3f = (unsigned short*)(ws + OFF_WT3);
  float* gst = (float*)(ws + OFF_GST);
  float* ss1 = (float*)(ws + OFF_SS1);
  float* ss2 = (float*)(ws + OFF_SS2);
  unsigned short* z = (unsigned short*)(ws + OFF_Z);

  hipMemsetAsync(gst, 0, 512 * sizeof(float), stream);
  k_prep<<<385, 256, 0, stream>>>(xyz, feat, W1, W2, W3, featB, xyz4, xn,
                                  wt1, wt2, wt3f, out);
  k_knn<<<4096, 256, 0, stream>>>(xyz, xn, knn);
  k_l1<<<2048, 256, 0, stream>>>(xyz4, featB, knn, out, wt1, b1, z);
  k_stats2<<<512, 256, 0, stream>>>(z, gst);           // layer-1 stats
  k_bnfin<<<1, 64, 0, stream>>>(gst, g1, be1, ss1);
  k_l2<<<2048, 256, 0, stream>>>(z, wt2, b2, ss1);
  k_stats2<<<512, 256, 0, stream>>>(z, gst + 128);     // layer-2 stats
  k_bnfin<<<1, 64, 0, stream>>>(gst + 128, g2, be2, ss2);
  k_l3<<<4096, 256, 0, stream>>>(z, wt3f, b3, ss2, g3, maxz, gst + 256);
  k_final<<<256, 256, 0, stream>>>(maxz, gst + 256, g3, be3, out);
}